// Round 4
// baseline (741.379 us; speedup 1.0000x reference)
//
#include <hip/hip_runtime.h>
#include <math.h>

#define NN 50000
#define EE 800000
#define DD 128
#define HH 4
#define CC 32
#define LL 2
#define TOT (EE + NN)
#define NG (TOT / 16)
#define NIT 8

typedef __attribute__((ext_vector_type(8))) short short8;
typedef __attribute__((ext_vector_type(4))) short short4v;
typedef __attribute__((ext_vector_type(4))) float f32x4;
typedef __attribute__((ext_vector_type(4))) unsigned short ushort4v;

__device__ inline short bf16c(float f){
    unsigned u = __float_as_uint(f);
    u = (u + 0x7fffu + ((u >> 16) & 1u)) >> 16;
    return (short)u;
}
__device__ inline float bf2f(unsigned short h){
    return __uint_as_float(((unsigned)h) << 16);
}

// ---------------- edge sorting (by dst) ----------------

__global__ __launch_bounds__(256) void k_hist(const int* __restrict__ dstA, int* __restrict__ deg){
    int e = blockIdx.x * 256 + threadIdx.x;
    if (e < EE) atomicAdd(&deg[dstA[e]], 1);
}

__global__ __launch_bounds__(1024) void k_scan1(const int* __restrict__ deg, int* __restrict__ offs,
                                                int* __restrict__ bsum){
    __shared__ int buf[1024];
    int t = threadIdx.x;
    int i = blockIdx.x * 1024 + t;
    int v = (i < NN) ? deg[i] : 0;
    buf[t] = v;
    __syncthreads();
    for (int off = 1; off < 1024; off <<= 1){
        int x = (t >= off) ? buf[t - off] : 0;
        __syncthreads();
        buf[t] += x;
        __syncthreads();
    }
    if (i < NN) offs[i + 1] = buf[t];
    if (t == 1023) bsum[blockIdx.x] = buf[1023];
    if (i == 0) offs[0] = 0;
}

__global__ void k_scan2(int* __restrict__ bsum, int nb){
    if (threadIdx.x == 0){
        int s = 0;
        for (int b = 0; b < nb; b++){ int v = bsum[b]; bsum[b] = s; s += v; }
    }
}

__global__ __launch_bounds__(1024) void k_scan3(int* __restrict__ offs, const int* __restrict__ bsum){
    int i = blockIdx.x * 1024 + threadIdx.x;
    if (i < NN) offs[i + 1] += bsum[i >> 10];
}

// scatter pass: only small scattered writes (perm/srcs2/dsts2, 4B each — their line
// working sets fit in L2 and write-combine). The 64B ea2s rows are NOT scattered here;
// they are produced by the gather pass k_gaea below (coalesced writes, line-exact reads).
__global__ __launch_bounds__(256) void k_scatter(const int* __restrict__ srcA, const int* __restrict__ dstA,
                                                 const int* __restrict__ offs, int* __restrict__ cnt,
                                                 int* __restrict__ srcs2, int* __restrict__ dsts2,
                                                 int* __restrict__ perm){
    int e = blockIdx.x * 256 + threadIdx.x;
    if (e < EE){
        int d = dstA[e];
        int pos = offs[d] + atomicAdd(&cnt[d], 1);
        srcs2[pos] = srcA[e];
        dsts2[pos] = d;
        perm[pos] = e;
    }
}

// gather pass: ea2s[pos] = bf16(ea[perm[pos]]). 8 threads/row; each ea row is exactly
// one 128B cache line (32 f32) -> random reads are line-granular with zero over-fetch;
// writes stream coalesced in sorted order (full 128B lines, no RMW amplification).
__global__ __launch_bounds__(256) void k_gaea(const float* __restrict__ ea, const int* __restrict__ perm,
                                              short* __restrict__ ea2s){
    int tid = blockIdx.x * 256 + threadIdx.x;   // EE*8
    int pos = tid >> 3, j = tid & 7;
    if (pos >= EE) return;
    int e = perm[pos];
    f32x4 v = *(const f32x4*)(ea + (size_t)e * 32 + j * 4);
    short4v h = {bf16c(v[0]), bf16c(v[1]), bf16c(v[2]), bf16c(v[3])};
    *(short4v*)(ea2s + (size_t)pos * 32 + j * 4) = h;
}

__global__ __launch_bounds__(256) void k_fill(int* __restrict__ srcs2, int* __restrict__ dsts2){
    int i = blockIdx.x * 256 + threadIdx.x;
    if (i < NN){ srcs2[EE + i] = i; dsts2[EE + i] = i; }
}

// loop_attr rows (appended at ea2s[EE..TOT)): mean of incoming sorted rows, bf16.
__global__ __launch_bounds__(256) void k_loopattr(short* __restrict__ ea2s, const int* __restrict__ offs){
    int tid = blockIdx.x * 256 + threadIdx.x;
    if (tid >= NN * CC) return;
    int n = tid >> 5, c = tid & 31;
    int b = offs[n], e = offs[n + 1];
    float s = 0.f;
    for (int p = b; p < e; ++p) s += bf2f((unsigned short)ea2s[(size_t)p * 32 + c]);
    ea2s[(size_t)(EE + n) * 32 + c] = bf16c(s / fmaxf((float)(e - b), 1.0f));
}

// ---------------- weight prep ----------------
// wt: Wt[c][k] = bf16(W[k][c]) for the 8 DxD matrices (Wl0,Wl1,Wr0,Wr1,w10,w11,w20,w21)

__global__ __launch_bounds__(256) void k_prepw(const float* __restrict__ Wl, const float* __restrict__ Wr,
                                               const float* __restrict__ w1, const float* __restrict__ w2,
                                               short* __restrict__ wt){
    int gid = blockIdx.x * 256 + threadIdx.x;      // 8 * 16384
    int mi = gid >> 14;
    int flat = gid & 16383;
    const float* base = (mi < 2) ? Wl : (mi < 4) ? Wr : (mi < 6) ? w1 : w2;
    const float* src = base + (size_t)(mi & 1) * 16384;
    int k = flat >> 7, c = flat & 127;
    wt[(size_t)mi * 16384 + c * 128 + k] = bf16c(src[flat]);
}

// weA: k_score A-fragments, laid out so af[t] = 16B vector load per lane.
// weA[((l*8 + t)*64 + lane)*8 + j] = bf16(We[l][k=q*8+j][d=t*16+m]), q=lane>>4, m=lane&15

__global__ __launch_bounds__(256) void k_prepwe(const float* __restrict__ We, short* __restrict__ weA){
    int gid = blockIdx.x * 256 + threadIdx.x;      // LL*8*64*8 = 8192
    if (gid >= LL * 4096) return;
    int j = gid & 7;
    int lane = (gid >> 3) & 63;
    int t = (gid >> 9) & 7;
    int l = gid >> 12;
    int q = lane >> 4, m = lane & 15;
    weA[gid] = bf16c(We[(size_t)l * 4096 + (q * 8 + j) * 128 + t * 16 + m]);
}

// nodes fp32 -> bf16
__global__ __launch_bounds__(256) void k_prepx(const float* __restrict__ x, short* __restrict__ xb){
    int i = blockIdx.x * 256 + threadIdx.x;        // over NN*DD/4
    if (i >= NN * DD / 4) return;
    f32x4 v = *(const f32x4*)(x + (size_t)i * 4);
    short4v h = {bf16c(v[0]), bf16c(v[1]), bf16c(v[2]), bf16c(v[3])};
    *(short4v*)(xb + (size_t)i * 4) = h;
}

// ---------------- MFMA GEMM: C[r][c] = act( sum_k X[r][k] W[k][c] + bias[c] ) ----------------
// mode bit 1: write f32 natural; bit 2: write bf16; bit 4: bf16 write uses the
// permuted "score gather" row layout: channel c -> ushort offset
//   (c>>5)*32 + ((c>>2)&3)*8 + ((c>>4)&1)*4 + (c&3)
// so that k_score lanes read 16B contiguous chunks and 4 q-lanes cover one 64B segment.

__global__ __launch_bounds__(256) void k_mg(const short* __restrict__ Xb, const short* __restrict__ Wt,
                                            const float* __restrict__ bv, float* __restrict__ Yf,
                                            unsigned short* __restrict__ Yb, int act, int mode){
    int lane = threadIdx.x & 63;
    int wave = threadIdx.x >> 6;
    int q = lane >> 4;
    int m = lane & 15;
    int cw0 = wave * 32;
    int r0 = blockIdx.x * 64;

    short8 af[2][4];
    #pragma unroll
    for (int ct = 0; ct < 2; ct++)
        #pragma unroll
        for (int ks = 0; ks < 4; ks++)
            af[ct][ks] = *(const short8*)(Wt + (size_t)(cw0 + ct * 16 + m) * 128 + ks * 32 + q * 8);

    f32x4 bq[2];
    #pragma unroll
    for (int ct = 0; ct < 2; ct++)
        bq[ct] = *(const f32x4*)(bv + cw0 + ct * 16 + q * 4);

    #pragma unroll
    for (int rt = 0; rt < 4; rt++){
        int r = r0 + rt * 16 + m;
        int rc = (r < NN) ? r : NN - 1;
        short8 bf[4];
        #pragma unroll
        for (int ks = 0; ks < 4; ks++)
            bf[ks] = *(const short8*)(Xb + (size_t)rc * 128 + ks * 32 + q * 8);

        f32x4 ac0 = {0.f, 0.f, 0.f, 0.f};
        f32x4 ac1 = {0.f, 0.f, 0.f, 0.f};
        #pragma unroll
        for (int ks = 0; ks < 4; ks++){
            ac0 = __builtin_amdgcn_mfma_f32_16x16x32_bf16(af[0][ks], bf[ks], ac0, 0, 0, 0);
            ac1 = __builtin_amdgcn_mfma_f32_16x16x32_bf16(af[1][ks], bf[ks], ac1, 0, 0, 0);
        }
        int rr = r0 + rt * 16 + m;
        if (rr < NN){
            #pragma unroll
            for (int ct = 0; ct < 2; ct++){
                f32x4 a = ct ? ac1 : ac0;
                f32x4 v;
                #pragma unroll
                for (int j = 0; j < 4; j++){
                    float x = a[j] + bq[ct][j];
                    if (act) x = fmaxf(x, 0.f);
                    v[j] = x;
                }
                int c0 = cw0 + ct * 16 + q * 4;
                if (mode & 1)
                    *(f32x4*)(Yf + (size_t)rr * 128 + c0) = v;
                if (mode & 2){
                    short4v h = {bf16c(v[0]), bf16c(v[1]), bf16c(v[2]), bf16c(v[3])};
                    int oo = (mode & 4) ? (((c0 >> 5) << 5) + (q << 3) + (((c0 >> 4) & 1) << 2))
                                        : c0;
                    *(short4v*)(Yb + (size_t)rr * 128 + oo) = h;
                }
            }
        }
    }
}

// ---------------- fused edge-score kernel: NIT adjacent tiles/wave, 2-stage pipeline ----
// alpha[pos][h] = sum_c att[h,c] * leaky(xl[src][c] + xr[dst][c] + (ea2s[pos]@We)[c])
// xlb/xrb in the permuted layout. Each wave walks NIT CONTIGUOUS tiles (preserves the
// dst-sorted locality window per XCD) and prefetches tile i+1's indices+gathers into
// the alternate register buffer while computing tile i (hides the ~900cy gather miss).

__global__ __launch_bounds__(256, 3) void k_score(const short* __restrict__ ea2s,
                                               const int* __restrict__ srcs2, const int* __restrict__ dsts2,
                                               const unsigned short* __restrict__ xlb,
                                               const unsigned short* __restrict__ xrb,
                                               const short* __restrict__ weA, const float* __restrict__ att,
                                               float* __restrict__ alpha){
    int lane = threadIdx.x & 63;
    int q = lane >> 4;
    int m = lane & 15;

    short8 af[8];
    #pragma unroll
    for (int t = 0; t < 8; t++)
        af[t] = *(const short8*)(weA + ((size_t)t * 64 + lane) * 8);
    f32x4 avv[8];
    #pragma unroll
    for (int t = 0; t < 8; t++)
        avv[t] = *(const f32x4*)(att + t * 16 + q * 4);

    int wid = (blockIdx.x * 256 + threadIdx.x) >> 6;
    int g0 = wid * NIT;
    if (g0 >= NG) return;

    short8 bx[2][4], br_[2][4], be[2];
    {
        int pos = g0 * 16 + m;
        int s = srcs2[pos], d = dsts2[pos];
        const unsigned short* px = xlb + (size_t)s * 128 + q * 8;
        const unsigned short* pr = xrb + (size_t)d * 128 + q * 8;
        #pragma unroll
        for (int u = 0; u < 4; u++){
            bx[0][u] = *(const short8*)(px + u * 32);
            br_[0][u] = *(const short8*)(pr + u * 32);
        }
        be[0] = __builtin_nontemporal_load((const short8*)(ea2s + (size_t)pos * 32 + q * 8));
    }

    #pragma unroll
    for (int i = 0; i < NIT; i++){
        int g = g0 + i;
        if (g >= NG) break;
        int b = i & 1;
        // prefetch next tile into the alternate buffer
        if (i + 1 < NIT && g + 1 < NG){
            int pos = (g + 1) * 16 + m;
            int s = srcs2[pos], d = dsts2[pos];
            const unsigned short* px = xlb + (size_t)s * 128 + q * 8;
            const unsigned short* pr = xrb + (size_t)d * 128 + q * 8;
            #pragma unroll
            for (int u = 0; u < 4; u++){
                bx[b ^ 1][u] = *(const short8*)(px + u * 32);
                br_[b ^ 1][u] = *(const short8*)(pr + u * 32);
            }
            be[b ^ 1] = __builtin_nontemporal_load((const short8*)(ea2s + (size_t)pos * 32 + q * 8));
        }
        // compute current tile
        float ps[4] = {0.f, 0.f, 0.f, 0.f};
        #pragma unroll
        for (int t = 0; t < 8; t++){
            f32x4 z = {0.f, 0.f, 0.f, 0.f};
            f32x4 c = __builtin_amdgcn_mfma_f32_16x16x32_bf16(af[t], be[b], z, 0, 0, 0);
            int u = t >> 1, lo = (t & 1) * 4;
            #pragma unroll
            for (int r = 0; r < 4; r++){
                float v = c[r] + bf2f((unsigned short)bx[b][u][lo + r]) + bf2f((unsigned short)br_[b][u][lo + r]);
                v = (v > 0.f) ? v : 0.2f * v;
                ps[t >> 1] = fmaf(avv[t][r], v, ps[t >> 1]);
            }
        }
        #pragma unroll
        for (int hh = 0; hh < 4; hh++){
            ps[hh] += __shfl_xor(ps[hh], 16);
            ps[hh] += __shfl_xor(ps[hh], 32);
        }
        if (lane < 16){
            f32x4 o = {ps[0], ps[1], ps[2], ps[3]};
            *(f32x4*)(alpha + ((size_t)g * 16 + m) * 4) = o;
        }
    }
}

// ---------------- GATv2 softmax + aggregation, chain-free ----------------
// Phase A (lanes j=lane&15 edge-slot, h=lane>>4): per-(node,head) max + denom from
// alpha; shfl-reduce within the 16-lane group -> (mx, inv) live in registers in
// exactly the lanes phase B needs (same h = lane>>4 grouping).
// Phase B (lane owns channels {2*lane,2*lane+1}): pure weighted gather-sum, 8-deep,
// NO cross-chunk dependency (the online-softmax rescale chain is gone).

__global__ __launch_bounds__(256) void k_gat2(const unsigned short* __restrict__ xlb,
                                              const int* __restrict__ srcs2, const int* __restrict__ offs,
                                              const float* __restrict__ alpha, const float* __restrict__ bias,
                                              unsigned short* __restrict__ out){
    int n = blockIdx.x * 4 + (threadIdx.x >> 6);
    int lane = threadIdx.x & 63;
    int h = lane >> 4;
    int j = lane & 15;

    int beg = offs[n];
    int deg = offs[n + 1] - beg;
    int cnt = deg + 1;   // + self-loop (position EE+n)

    // ---- phase A: max + denominator per (n, h) ----
    float mx = -INFINITY;
    for (int i = j; i < cnt; i += 16){
        int p = (i < deg) ? beg + i : EE + n;
        mx = fmaxf(mx, alpha[(size_t)p * 4 + h]);
    }
    mx = fmaxf(mx, __shfl_xor(mx, 1));
    mx = fmaxf(mx, __shfl_xor(mx, 2));
    mx = fmaxf(mx, __shfl_xor(mx, 4));
    mx = fmaxf(mx, __shfl_xor(mx, 8));
    float sm = 0.f;
    for (int i = j; i < cnt; i += 16){
        int p = (i < deg) ? beg + i : EE + n;
        sm += __expf(alpha[(size_t)p * 4 + h] - mx);
    }
    sm += __shfl_xor(sm, 1);
    sm += __shfl_xor(sm, 2);
    sm += __shfl_xor(sm, 4);
    sm += __shfl_xor(sm, 8);
    float inv = 1.f / (sm + 1e-16f);

    // ---- phase B: weighted aggregation ----
    int c0 = lane * 2;
    int po = ((c0 >> 5) << 5) + (((c0 >> 2) & 3) << 3) + (((c0 >> 4) & 1) << 2) + (c0 & 3);
    float A0 = 0.f, A1 = 0.f;
    for (int i = 0; i < cnt; i += 8){
        float w[8]; unsigned x[8];
        #pragma unroll
        for (int u = 0; u < 8; u++){
            int iu = i + u;
            int p = (iu < deg) ? beg + iu : EE + n;
            float a = alpha[(size_t)p * 4 + h];
            int s = srcs2[p];
            x[u] = *(const unsigned*)(xlb + (size_t)s * 128 + po);
            w[u] = (iu < cnt) ? __expf(a - mx) * inv : 0.f;
        }
        #pragma unroll
        for (int u = 0; u < 8; u++){
            A0 = fmaf(w[u], bf2f((unsigned short)(x[u] & 0xffffu)), A0);
            A1 = fmaf(w[u], bf2f((unsigned short)(x[u] >> 16)), A1);
        }
    }
    float v0 = A0 + bias[c0];
    float v1 = A1 + bias[c0 + 1];
    unsigned o = ((unsigned)(unsigned short)bf16c(v0)) | (((unsigned)(unsigned short)bf16c(v1)) << 16);
    *(unsigned*)(out + (size_t)n * 128 + c0) = o;
}

// ---------------- driver ----------------

extern "C" void kernel_launch(void* const* d_in, const int* in_sizes, int n_in,
                              void* d_out, int out_size, void* d_ws, size_t ws_size,
                              hipStream_t stream){
    const float* nodes = (const float*)d_in[0];
    const int*   ei    = (const int*)d_in[1];
    const float* ea    = (const float*)d_in[2];
    const float* Wl    = (const float*)d_in[3];
    const float* bl    = (const float*)d_in[4];
    const float* Wr    = (const float*)d_in[5];
    const float* br    = (const float*)d_in[6];
    const float* We    = (const float*)d_in[7];
    const float* att   = (const float*)d_in[8];
    const float* bias  = (const float*)d_in[9];
    const float* w1    = (const float*)d_in[10];
    const float* b1    = (const float*)d_in[11];
    const float* w2    = (const float*)d_in[12];
    const float* b2    = (const float*)d_in[13];
    const int* srcA = ei;
    const int* dstA = ei + EE;

    char* ws = (char*)d_ws;
    size_t off = 0;
    auto alloc = [&](size_t bytes) -> char* {
        off = (off + 255) & ~(size_t)255;
        char* p = ws + off;
        off += bytes;
        return p;
    };
    int*   deg   = (int*)alloc(NN * 4);
    int*   cnt   = (int*)alloc(NN * 4);
    int*   offs  = (int*)alloc((NN + 1) * 4);
    int*   bsum  = (int*)alloc(64 * 4);
    int*   srcs2 = (int*)alloc((size_t)TOT * 4);
    int*   dsts2 = (int*)alloc((size_t)TOT * 4);
    int*   perm  = (int*)alloc((size_t)EE * 4);
    short* ea2s  = (short*)alloc((size_t)TOT * CC * 2);
    float* alpha = (float*)alloc((size_t)TOT * 4 * 4);
    short* wt    = (short*)alloc((size_t)8 * 16384 * 2);          // 8 transposed bf16 weights
    short* weA   = (short*)alloc((size_t)LL * 4096 * 2);          // k_score A-frag table
    short* xb    = (short*)alloc((size_t)NN * DD * 2);            // current x, bf16
    unsigned short* xlb = (unsigned short*)alloc((size_t)NN * DD * 2);
    unsigned short* xrb = (unsigned short*)alloc((size_t)NN * DD * 2);
    unsigned short* bgb = (unsigned short*)alloc((size_t)NN * DD * 2);  // gat2 out, bf16
    unsigned short* bhb = (unsigned short*)alloc((size_t)NN * DD * 2);  // MLP hidden, bf16
    unsigned short* bxb = (unsigned short*)alloc((size_t)NN * DD * 2);  // inter-layer x, bf16

    hipMemsetAsync(deg, 0, NN * 4, stream);
    hipMemsetAsync(cnt, 0, NN * 4, stream);
    k_hist<<<(EE + 255) / 256, 256, 0, stream>>>(dstA, deg);
    int nb = (NN + 1023) / 1024;
    k_scan1<<<nb, 1024, 0, stream>>>(deg, offs, bsum);
    k_scan2<<<1, 64, 0, stream>>>(bsum, nb);
    k_scan3<<<nb, 1024, 0, stream>>>(offs, bsum);
    k_scatter<<<(EE + 255) / 256, 256, 0, stream>>>(srcA, dstA, offs, cnt, srcs2, dsts2, perm);
    k_gaea<<<(EE * 8 + 255) / 256, 256, 0, stream>>>(ea, perm, ea2s);
    k_fill<<<(NN + 255) / 256, 256, 0, stream>>>(srcs2, dsts2);
    k_loopattr<<<(NN * CC + 255) / 256, 256, 0, stream>>>(ea2s, offs);
    k_prepw<<<8 * 16384 / 256, 256, 0, stream>>>(Wl, Wr, w1, w2, wt);
    k_prepwe<<<(LL * 4096 + 255) / 256, 256, 0, stream>>>(We, weA);
    k_prepx<<<(NN * DD / 4 + 255) / 256, 256, 0, stream>>>(nodes, xb);

    const int GB = (NN + 63) / 64;   // 782
    const int SCORE_WAVES = (NG + NIT - 1) / NIT;    // one wave per NIT adjacent tiles
    const int SCORE_BLOCKS = (SCORE_WAVES + 3) / 4;  // 4 waves per block
    short* wtWl = wt;
    short* wtWr = wt + 2 * 16384;
    short* wtw1 = wt + 4 * 16384;
    short* wtw2 = wt + 6 * 16384;

    const short* x = xb;
    for (int l = 0; l < LL; l++){
        // xl/xr projections written in the permuted score-gather layout (mode 2|4)
        k_mg<<<GB, 256, 0, stream>>>(x, wtWl + l * 16384, bl + l * DD, nullptr, xlb, 0, 6);
        k_mg<<<GB, 256, 0, stream>>>(x, wtWr + l * 16384, br + l * DD, nullptr, xrb, 0, 6);
        k_score<<<SCORE_BLOCKS, 256, 0, stream>>>(ea2s, srcs2, dsts2, xlb, xrb,
                                                  weA + l * 4096, att + l * HH * CC, alpha);
        k_gat2<<<NN / 4, 256, 0, stream>>>(xlb, srcs2, offs, alpha, bias + l * DD, bgb);
        k_mg<<<GB, 256, 0, stream>>>((const short*)bgb, wtw1 + l * 16384, b1 + l * DD, nullptr, bhb, 1, 2);
        if (l == LL - 1)
            k_mg<<<GB, 256, 0, stream>>>((const short*)bhb, wtw2 + l * 16384, b2 + l * DD,
                                         (float*)d_out, nullptr, 0, 1);
        else
            k_mg<<<GB, 256, 0, stream>>>((const short*)bhb, wtw2 + l * 16384, b2 + l * DD,
                                         nullptr, bxb, 0, 2);
        x = (const short*)bxb;
    }
}

// Round 5
// 718.079 us; speedup vs baseline: 1.0324x; 1.0324x over previous
//
#include <hip/hip_runtime.h>
#include <math.h>

#define NN 50000
#define EE 800000
#define DD 128
#define HH 4
#define CC 32
#define LL 2
#define TOT (EE + NN)
#define NG (TOT / 16)

typedef __attribute__((ext_vector_type(8))) short short8;
typedef __attribute__((ext_vector_type(4))) short short4v;
typedef __attribute__((ext_vector_type(4))) float f32x4;
typedef __attribute__((ext_vector_type(4))) unsigned short ushort4v;

__device__ inline short bf16c(float f){
    unsigned u = __float_as_uint(f);
    u = (u + 0x7fffu + ((u >> 16) & 1u)) >> 16;
    return (short)u;
}
__device__ inline float bf2f(unsigned short h){
    return __uint_as_float(((unsigned)h) << 16);
}

// ---------------- edge sorting (by dst) ----------------

__global__ __launch_bounds__(256) void k_hist(const int* __restrict__ dstA, int* __restrict__ deg){
    int e = blockIdx.x * 256 + threadIdx.x;
    if (e < EE) atomicAdd(&deg[dstA[e]], 1);
}

__global__ __launch_bounds__(1024) void k_scan1(const int* __restrict__ deg, int* __restrict__ offs,
                                                int* __restrict__ bsum){
    __shared__ int buf[1024];
    int t = threadIdx.x;
    int i = blockIdx.x * 1024 + t;
    int v = (i < NN) ? deg[i] : 0;
    buf[t] = v;
    __syncthreads();
    for (int off = 1; off < 1024; off <<= 1){
        int x = (t >= off) ? buf[t - off] : 0;
        __syncthreads();
        buf[t] += x;
        __syncthreads();
    }
    if (i < NN) offs[i + 1] = buf[t];
    if (t == 1023) bsum[blockIdx.x] = buf[1023];
    if (i == 0) offs[0] = 0;
}

__global__ void k_scan2(int* __restrict__ bsum, int nb){
    if (threadIdx.x == 0){
        int s = 0;
        for (int b = 0; b < nb; b++){ int v = bsum[b]; bsum[b] = s; s += v; }
    }
}

__global__ __launch_bounds__(1024) void k_scan3(int* __restrict__ offs, const int* __restrict__ bsum){
    int i = blockIdx.x * 1024 + threadIdx.x;
    if (i < NN) offs[i + 1] += bsum[i >> 10];
}

// scatter pass (+ merged self-loop index fill): only small scattered 4B writes
// (perm/srcs2/dsts2 — their line working sets fit in L2 and write-combine).
// Edge-attr rows are NOT materialized in sorted order at all: k_score gathers
// them straight from ea via perm (line-granular 128B reads).
__global__ __launch_bounds__(256) void k_scatter(const int* __restrict__ srcA, const int* __restrict__ dstA,
                                                 const int* __restrict__ offs, int* __restrict__ cnt,
                                                 int* __restrict__ srcs2, int* __restrict__ dsts2,
                                                 int* __restrict__ perm){
    int e = blockIdx.x * 256 + threadIdx.x;
    if (e < EE){
        int d = dstA[e];
        int pos = offs[d] + atomicAdd(&cnt[d], 1);
        srcs2[pos] = srcA[e];
        dsts2[pos] = d;
        perm[pos] = e;
    } else {
        int i = e - EE;
        if (i < NN){ srcs2[EE + i] = i; dsts2[EE + i] = i; }
    }
}

// loopf[n][c] = mean over incoming edges of ea[e][c], kept in f32.
// 32 lanes per node read each edge row as one full 128B line (random but
// line-exact); writes coalesced. Also pre-warms L3 with ea for k_score.
__global__ __launch_bounds__(256) void k_loopf(const float* __restrict__ ea, const int* __restrict__ perm,
                                               const int* __restrict__ offs, float* __restrict__ loopf){
    int tid = blockIdx.x * 256 + threadIdx.x;
    if (tid >= NN * CC) return;
    int n = tid >> 5, c = tid & 31;
    int b = offs[n], e = offs[n + 1];
    float s = 0.f;
    for (int p = b; p < e; ++p){
        int ed = perm[p];
        s += ea[(size_t)ed * 32 + c];
    }
    loopf[(size_t)n * 32 + c] = s / fmaxf((float)(e - b), 1.0f);
}

// ---------------- merged weight/input prep ----------------
// region 1: wt[c][k] = bf16(W[k][c]) for 8 DxD matrices (Wl0,Wl1,Wr0,Wr1,w10,w11,w20,w21)
// region 2: weA k_score A-fragments: weA[((l*8+t)*64+lane)*8+j] = bf16(We[l][q*8+j][t*16+m])
// region 3: nodes fp32 -> bf16
#define PREPW_T (8 * 16384)
#define PREPWE_T (LL * 4096)
#define PREPX_T (NN * DD / 4)

__global__ __launch_bounds__(256) void k_prep(const float* __restrict__ Wl, const float* __restrict__ Wr,
                                              const float* __restrict__ w1, const float* __restrict__ w2,
                                              short* __restrict__ wt,
                                              const float* __restrict__ We, short* __restrict__ weA,
                                              const float* __restrict__ x, short* __restrict__ xb){
    int gid = blockIdx.x * 256 + threadIdx.x;
    if (gid < PREPW_T){
        int mi = gid >> 14;
        int flat = gid & 16383;
        const float* base = (mi < 2) ? Wl : (mi < 4) ? Wr : (mi < 6) ? w1 : w2;
        const float* src = base + (size_t)(mi & 1) * 16384;
        int k = flat >> 7, c = flat & 127;
        wt[(size_t)mi * 16384 + c * 128 + k] = bf16c(src[flat]);
    } else if (gid < PREPW_T + PREPWE_T){
        int g2 = gid - PREPW_T;
        int j = g2 & 7;
        int lane = (g2 >> 3) & 63;
        int t = (g2 >> 9) & 7;
        int l = g2 >> 12;
        int q = lane >> 4, m = lane & 15;
        weA[g2] = bf16c(We[(size_t)l * 4096 + (q * 8 + j) * 128 + t * 16 + m]);
    } else {
        int i = gid - PREPW_T - PREPWE_T;
        if (i < PREPX_T){
            f32x4 v = *(const f32x4*)(x + (size_t)i * 4);
            short4v h = {bf16c(v[0]), bf16c(v[1]), bf16c(v[2]), bf16c(v[3])};
            *(short4v*)(xb + (size_t)i * 4) = h;
        }
    }
}

// ---------------- MFMA GEMM: C[r][c] = act( sum_k X[r][k] W[k][c] + bias[c] ) ----------------
// mode bit 1: write f32 natural; bit 2: write bf16; bit 4: bf16 write uses the
// permuted "score gather" row layout: channel c -> ushort offset
//   (c>>5)*32 + ((c>>2)&3)*8 + ((c>>4)&1)*4 + (c&3)
// so that k_score lanes read 16B contiguous chunks and 4 q-lanes cover one 64B segment.

__global__ __launch_bounds__(256) void k_mg(const short* __restrict__ Xb, const short* __restrict__ Wt,
                                            const float* __restrict__ bv, float* __restrict__ Yf,
                                            unsigned short* __restrict__ Yb, int act, int mode){
    int lane = threadIdx.x & 63;
    int wave = threadIdx.x >> 6;
    int q = lane >> 4;
    int m = lane & 15;
    int cw0 = wave * 32;
    int r0 = blockIdx.x * 64;

    short8 af[2][4];
    #pragma unroll
    for (int ct = 0; ct < 2; ct++)
        #pragma unroll
        for (int ks = 0; ks < 4; ks++)
            af[ct][ks] = *(const short8*)(Wt + (size_t)(cw0 + ct * 16 + m) * 128 + ks * 32 + q * 8);

    f32x4 bq[2];
    #pragma unroll
    for (int ct = 0; ct < 2; ct++)
        bq[ct] = *(const f32x4*)(bv + cw0 + ct * 16 + q * 4);

    #pragma unroll
    for (int rt = 0; rt < 4; rt++){
        int r = r0 + rt * 16 + m;
        int rc = (r < NN) ? r : NN - 1;
        short8 bf[4];
        #pragma unroll
        for (int ks = 0; ks < 4; ks++)
            bf[ks] = *(const short8*)(Xb + (size_t)rc * 128 + ks * 32 + q * 8);

        f32x4 ac0 = {0.f, 0.f, 0.f, 0.f};
        f32x4 ac1 = {0.f, 0.f, 0.f, 0.f};
        #pragma unroll
        for (int ks = 0; ks < 4; ks++){
            ac0 = __builtin_amdgcn_mfma_f32_16x16x32_bf16(af[0][ks], bf[ks], ac0, 0, 0, 0);
            ac1 = __builtin_amdgcn_mfma_f32_16x16x32_bf16(af[1][ks], bf[ks], ac1, 0, 0, 0);
        }
        int rr = r0 + rt * 16 + m;
        if (rr < NN){
            #pragma unroll
            for (int ct = 0; ct < 2; ct++){
                f32x4 a = ct ? ac1 : ac0;
                f32x4 v;
                #pragma unroll
                for (int j = 0; j < 4; j++){
                    float x = a[j] + bq[ct][j];
                    if (act) x = fmaxf(x, 0.f);
                    v[j] = x;
                }
                int c0 = cw0 + ct * 16 + q * 4;
                if (mode & 1)
                    *(f32x4*)(Yf + (size_t)rr * 128 + c0) = v;
                if (mode & 2){
                    short4v h = {bf16c(v[0]), bf16c(v[1]), bf16c(v[2]), bf16c(v[3])};
                    int oo = (mode & 4) ? (((c0 >> 5) << 5) + (q << 3) + (((c0 >> 4) & 1) << 2))
                                        : c0;
                    *(short4v*)(Yb + (size_t)rr * 128 + oo) = h;
                }
            }
        }
    }
}

// ---------------- fused edge-score kernel: 2 MFMA tiles per wave, one-shot ----------------
// alpha[pos][h] = sum_c att[h,c] * leaky(xl[src][c] + xr[dst][c] + (ea[perm[pos]]@We)[c])
// B-operand rows come straight from ea (f32, perm-gathered: 4 q-lanes x 32B = one full
// 128B line per row) or from loopf for self-loop tiles; converted bf16 in-register.
// xlb/xrb in the permuted layout (see k_mg). NON-persistent launch: the HW dispatcher
// provides a moving window over the dst-sorted tiles (L2 locality for xrb/alpha).

__global__ __launch_bounds__(256) void k_score(const float* __restrict__ ea, const float* __restrict__ loopf,
                                               const int* __restrict__ perm,
                                               const int* __restrict__ srcs2, const int* __restrict__ dsts2,
                                               const unsigned short* __restrict__ xlb,
                                               const unsigned short* __restrict__ xrb,
                                               const short* __restrict__ weA, const float* __restrict__ att,
                                               float* __restrict__ alpha){
    int lane = threadIdx.x & 63;
    int q = lane >> 4;
    int m = lane & 15;

    short8 af[8];
    #pragma unroll
    for (int t = 0; t < 8; t++)
        af[t] = *(const short8*)(weA + ((size_t)t * 64 + lane) * 8);

    int wid = (blockIdx.x * 256 + threadIdx.x) >> 6;
    int g = wid * 2;
    if (g >= NG) return;

    bool hB = (g + 1) < NG;
    int posA = g * 16 + m;
    int posB = hB ? posA + 16 : posA;

    int sA = srcs2[posA], dA = dsts2[posA];
    int sB = srcs2[posB], dB = dsts2[posB];
    int eA = perm[posA < EE ? posA : 0];
    int eB = perm[posB < EE ? posB : 0];

    // gathers: 16B/lane, 4 q-lanes contiguous per row (permuted layout)
    const unsigned short* pxA = xlb + (size_t)sA * 128 + q * 8;
    const unsigned short* prA = xrb + (size_t)dA * 128 + q * 8;
    const unsigned short* pxB = xlb + (size_t)sB * 128 + q * 8;
    const unsigned short* prB = xrb + (size_t)dB * 128 + q * 8;
    short8 gxA[4], grA[4], gxB[4], grB[4];
    #pragma unroll
    for (int u = 0; u < 4; u++){
        gxA[u] = *(const short8*)(pxA + u * 32);
        grA[u] = *(const short8*)(prA + u * 32);
        gxB[u] = *(const short8*)(pxB + u * 32);
        grB[u] = *(const short8*)(prB + u * 32);
    }

    // B-operand rows from ea / loopf, f32 -> bf16 in-register
    const float* rpA = (posA < EE) ? (ea + (size_t)eA * 32) : (loopf + (size_t)(posA - EE) * 32);
    const float* rpB = (posB < EE) ? (ea + (size_t)eB * 32) : (loopf + (size_t)(posB - EE) * 32);
    f32x4 va0 = *(const f32x4*)(rpA + q * 8);
    f32x4 va1 = *(const f32x4*)(rpA + q * 8 + 4);
    f32x4 vb0 = *(const f32x4*)(rpB + q * 8);
    f32x4 vb1 = *(const f32x4*)(rpB + q * 8 + 4);
    short8 bfA = {bf16c(va0[0]), bf16c(va0[1]), bf16c(va0[2]), bf16c(va0[3]),
                  bf16c(va1[0]), bf16c(va1[1]), bf16c(va1[2]), bf16c(va1[3])};
    short8 bfB = {bf16c(vb0[0]), bf16c(vb0[1]), bf16c(vb0[2]), bf16c(vb0[3]),
                  bf16c(vb1[0]), bf16c(vb1[1]), bf16c(vb1[2]), bf16c(vb1[3])};

    float psA[4] = {0.f,0.f,0.f,0.f}, psB[4] = {0.f,0.f,0.f,0.f};
    #pragma unroll
    for (int t = 0; t < 8; t++){
        f32x4 z = {0.f,0.f,0.f,0.f};
        f32x4 cA = __builtin_amdgcn_mfma_f32_16x16x32_bf16(af[t], bfA, z, 0, 0, 0);
        f32x4 cB = __builtin_amdgcn_mfma_f32_16x16x32_bf16(af[t], bfB, z, 0, 0, 0);
        f32x4 av = *(const f32x4*)(att + t * 16 + q * 4);
        int u = t >> 1, lo = (t & 1) * 4;
        #pragma unroll
        for (int r = 0; r < 4; r++){
            float ma = cA[r] + bf2f((unsigned short)gxA[u][lo + r]) + bf2f((unsigned short)grA[u][lo + r]);
            float mb = cB[r] + bf2f((unsigned short)gxB[u][lo + r]) + bf2f((unsigned short)grB[u][lo + r]);
            ma = (ma > 0.f) ? ma : 0.2f * ma;
            mb = (mb > 0.f) ? mb : 0.2f * mb;
            psA[t >> 1] = fmaf(av[r], ma, psA[t >> 1]);
            psB[t >> 1] = fmaf(av[r], mb, psB[t >> 1]);
        }
    }
    #pragma unroll
    for (int h = 0; h < 4; h++){
        psA[h] += __shfl_xor(psA[h], 16);
        psA[h] += __shfl_xor(psA[h], 32);
        psB[h] += __shfl_xor(psB[h], 16);
        psB[h] += __shfl_xor(psB[h], 32);
    }
    if (lane < 16){
        f32x4 oA = {psA[0], psA[1], psA[2], psA[3]};
        *(f32x4*)(alpha + (size_t)posA * 4) = oA;
        if (hB){
            f32x4 oB = {psB[0], psB[1], psB[2], psB[3]};
            *(f32x4*)(alpha + (size_t)posB * 4) = oB;
        }
    }
}

// ---------------- GATv2 softmax + aggregation (bf16 gathers, 2 adjacent ch/lane) ----------------
// lane owns channels {2*lane, 2*lane+1}; both in head h = lane>>4 -> single softmax state.
// xlb is in the permuted layout; per-lane ushort offset computed from channel.

__global__ __launch_bounds__(256) void k_gat2(const unsigned short* __restrict__ xlb,
                                              const int* __restrict__ srcs2, const int* __restrict__ offs,
                                              const float* __restrict__ alpha, const float* __restrict__ bias,
                                              unsigned short* __restrict__ out){
    int n = blockIdx.x * 4 + (threadIdx.x >> 6);
    int lane = threadIdx.x & 63;
    int c0 = lane * 2;
    int h = lane >> 4;
    // permuted ushort offset of channels {c0, c0+1} (adjacent in permuted layout since c0 even)
    int po = ((c0 >> 5) << 5) + (((c0 >> 2) & 3) << 3) + (((c0 >> 4) & 1) << 2) + (c0 & 3);

    int beg = offs[n];
    int deg = offs[n + 1] - beg;
    int cnt = deg + 1;   // + self-loop (position EE+n)

    float M = -INFINITY, S = 0.f, A0 = 0.f, A1 = 0.f;

    for (int i = 0; i < cnt; i += 4){
        float a[4]; unsigned x[4];
        #pragma unroll
        for (int u = 0; u < 4; u++){
            int iu = i + u;
            int p = (iu < deg) ? beg + iu : EE + n;
            int s = srcs2[p];
            a[u] = alpha[(size_t)p * 4 + h];
            x[u] = *(const unsigned*)(xlb + (size_t)s * 128 + po);
            if (iu >= cnt) a[u] = -INFINITY;
        }
        float nM = fmaxf(fmaxf(fmaxf(a[0], a[1]), fmaxf(a[2], a[3])), M);
        float rs = __expf(M - nM);
        float w0 = __expf(a[0] - nM);
        float w1 = __expf(a[1] - nM);
        float w2 = __expf(a[2] - nM);
        float w3 = __expf(a[3] - nM);
        S = S * rs + w0 + w1 + w2 + w3;
        A0 = A0 * rs + w0 * bf2f((unsigned short)(x[0] & 0xffffu))
                     + w1 * bf2f((unsigned short)(x[1] & 0xffffu))
                     + w2 * bf2f((unsigned short)(x[2] & 0xffffu))
                     + w3 * bf2f((unsigned short)(x[3] & 0xffffu));
        A1 = A1 * rs + w0 * bf2f((unsigned short)(x[0] >> 16))
                     + w1 * bf2f((unsigned short)(x[1] >> 16))
                     + w2 * bf2f((unsigned short)(x[2] >> 16))
                     + w3 * bf2f((unsigned short)(x[3] >> 16));
        M = nM;
    }
    float inv = 1.f / (S + 1e-16f);
    float v0 = A0 * inv + bias[c0];
    float v1 = A1 * inv + bias[c0 + 1];
    unsigned o = ((unsigned)(unsigned short)bf16c(v0)) | (((unsigned)(unsigned short)bf16c(v1)) << 16);
    *(unsigned*)(out + (size_t)n * 128 + c0) = o;
}

// ---------------- driver ----------------

extern "C" void kernel_launch(void* const* d_in, const int* in_sizes, int n_in,
                              void* d_out, int out_size, void* d_ws, size_t ws_size,
                              hipStream_t stream){
    const float* nodes = (const float*)d_in[0];
    const int*   ei    = (const int*)d_in[1];
    const float* ea    = (const float*)d_in[2];
    const float* Wl    = (const float*)d_in[3];
    const float* bl    = (const float*)d_in[4];
    const float* Wr    = (const float*)d_in[5];
    const float* br    = (const float*)d_in[6];
    const float* We    = (const float*)d_in[7];
    const float* att   = (const float*)d_in[8];
    const float* bias  = (const float*)d_in[9];
    const float* w1    = (const float*)d_in[10];
    const float* b1    = (const float*)d_in[11];
    const float* w2    = (const float*)d_in[12];
    const float* b2    = (const float*)d_in[13];
    const int* srcA = ei;
    const int* dstA = ei + EE;

    char* ws = (char*)d_ws;
    size_t off = 0;
    auto alloc = [&](size_t bytes) -> char* {
        off = (off + 255) & ~(size_t)255;
        char* p = ws + off;
        off += bytes;
        return p;
    };
    int*   deg   = (int*)alloc(NN * 4);
    int*   cnt   = (int*)alloc(NN * 4);
    int*   offs  = (int*)alloc((NN + 1) * 4);
    int*   bsum  = (int*)alloc(64 * 4);
    int*   srcs2 = (int*)alloc((size_t)TOT * 4);
    int*   dsts2 = (int*)alloc((size_t)TOT * 4);
    int*   perm  = (int*)alloc((size_t)EE * 4);
    float* loopf = (float*)alloc((size_t)NN * CC * 4);            // self-loop attr means, f32
    float* alpha = (float*)alloc((size_t)TOT * 4 * 4);
    short* wt    = (short*)alloc((size_t)8 * 16384 * 2);          // 8 transposed bf16 weights
    short* weA   = (short*)alloc((size_t)LL * 4096 * 2);          // k_score A-frag table
    short* xb    = (short*)alloc((size_t)NN * DD * 2);            // current x, bf16
    unsigned short* xlb = (unsigned short*)alloc((size_t)NN * DD * 2);
    unsigned short* xrb = (unsigned short*)alloc((size_t)NN * DD * 2);
    unsigned short* bgb = (unsigned short*)alloc((size_t)NN * DD * 2);  // gat2 out, bf16
    unsigned short* bhb = (unsigned short*)alloc((size_t)NN * DD * 2);  // MLP hidden, bf16
    unsigned short* bxb = (unsigned short*)alloc((size_t)NN * DD * 2);  // inter-layer x, bf16

    hipMemsetAsync(deg, 0, NN * 4, stream);
    hipMemsetAsync(cnt, 0, NN * 4, stream);
    k_hist<<<(EE + 255) / 256, 256, 0, stream>>>(dstA, deg);
    int nb = (NN + 1023) / 1024;
    k_scan1<<<nb, 1024, 0, stream>>>(deg, offs, bsum);
    k_scan2<<<1, 64, 0, stream>>>(bsum, nb);
    k_scan3<<<nb, 1024, 0, stream>>>(offs, bsum);
    k_scatter<<<(EE + NN + 255) / 256, 256, 0, stream>>>(srcA, dstA, offs, cnt, srcs2, dsts2, perm);
    k_loopf<<<(NN * CC + 255) / 256, 256, 0, stream>>>(ea, perm, offs, loopf);
    k_prep<<<(PREPW_T + PREPWE_T + PREPX_T + 255) / 256, 256, 0, stream>>>(
        Wl, Wr, w1, w2, wt, We, weA, nodes, xb);

    const int GB = (NN + 63) / 64;   // 782
    const int SCORE_WAVES = (NG + 1) / 2;            // one wave per 2 adjacent tiles
    const int SCORE_BLOCKS = (SCORE_WAVES + 3) / 4;  // 4 waves per block
    short* wtWl = wt;
    short* wtWr = wt + 2 * 16384;
    short* wtw1 = wt + 4 * 16384;
    short* wtw2 = wt + 6 * 16384;

    const short* x = xb;
    for (int l = 0; l < LL; l++){
        // xl/xr projections written in the permuted score-gather layout (mode 2|4)
        k_mg<<<GB, 256, 0, stream>>>(x, wtWl + l * 16384, bl + l * DD, nullptr, xlb, 0, 6);
        k_mg<<<GB, 256, 0, stream>>>(x, wtWr + l * 16384, br + l * DD, nullptr, xrb, 0, 6);
        k_score<<<SCORE_BLOCKS, 256, 0, stream>>>(ea, loopf, perm, srcs2, dsts2, xlb, xrb,
                                                  weA + l * 4096, att + l * HH * CC, alpha);
        k_gat2<<<NN / 4, 256, 0, stream>>>(xlb, srcs2, offs, alpha, bias + l * DD, bgb);
        k_mg<<<GB, 256, 0, stream>>>((const short*)bgb, wtw1 + l * 16384, b1 + l * DD, nullptr, bhb, 1, 2);
        if (l == LL - 1)
            k_mg<<<GB, 256, 0, stream>>>((const short*)bhb, wtw2 + l * 16384, b2 + l * DD,
                                         (float*)d_out, nullptr, 0, 1);
        else
            k_mg<<<GB, 256, 0, stream>>>((const short*)bhb, wtw2 + l * 16384, b2 + l * DD,
                                         nullptr, bxb, 0, 2);
        x = (const short*)bxb;
    }
}

// Round 6
// 683.354 us; speedup vs baseline: 1.0849x; 1.0508x over previous
//
#include <hip/hip_runtime.h>
#include <math.h>

#define NN 50000
#define EE 800000
#define DD 128
#define HH 4
#define CC 32
#define LL 2
#define TOT (EE + NN)
#define NG (TOT / 16)

typedef __attribute__((ext_vector_type(8))) short short8;
typedef __attribute__((ext_vector_type(4))) short short4v;
typedef __attribute__((ext_vector_type(4))) float f32x4;
typedef __attribute__((ext_vector_type(4))) unsigned short ushort4v;

__device__ inline short bf16c(float f){
    unsigned u = __float_as_uint(f);
    u = (u + 0x7fffu + ((u >> 16) & 1u)) >> 16;
    return (short)u;
}
__device__ inline float bf2f(unsigned short h){
    return __uint_as_float(((unsigned)h) << 16);
}

// ---------------- edge sorting (by dst) ----------------

__global__ __launch_bounds__(256) void k_hist(const int* __restrict__ dstA, int* __restrict__ deg){
    int e = blockIdx.x * 256 + threadIdx.x;
    if (e < EE) atomicAdd(&deg[dstA[e]], 1);
}

__global__ __launch_bounds__(1024) void k_scan1(const int* __restrict__ deg, int* __restrict__ offs,
                                                int* __restrict__ bsum){
    __shared__ int buf[1024];
    int t = threadIdx.x;
    int i = blockIdx.x * 1024 + t;
    int v = (i < NN) ? deg[i] : 0;
    buf[t] = v;
    __syncthreads();
    for (int off = 1; off < 1024; off <<= 1){
        int x = (t >= off) ? buf[t - off] : 0;
        __syncthreads();
        buf[t] += x;
        __syncthreads();
    }
    if (i < NN) offs[i + 1] = buf[t];
    if (t == 1023) bsum[blockIdx.x] = buf[1023];
    if (i == 0) offs[0] = 0;
}

__global__ void k_scan2(int* __restrict__ bsum, int nb){
    if (threadIdx.x == 0){
        int s = 0;
        for (int b = 0; b < nb; b++){ int v = bsum[b]; bsum[b] = s; s += v; }
    }
}

__global__ __launch_bounds__(1024) void k_scan3(int* __restrict__ offs, const int* __restrict__ bsum){
    int i = blockIdx.x * 1024 + threadIdx.x;
    if (i < NN) offs[i + 1] += bsum[i >> 10];
}

// scatter pass (+ merged self-loop index fill): only small scattered 4B writes
// (perm/srcs2/dsts2 — their line working sets fit in L2 and write-combine).
// Edge-attr rows are NOT materialized in sorted order at all: k_score gathers
// them straight from ea via perm (line-granular 128B reads).
__global__ __launch_bounds__(256) void k_scatter(const int* __restrict__ srcA, const int* __restrict__ dstA,
                                                 const int* __restrict__ offs, int* __restrict__ cnt,
                                                 int* __restrict__ srcs2, int* __restrict__ dsts2,
                                                 int* __restrict__ perm){
    int e = blockIdx.x * 256 + threadIdx.x;
    if (e < EE){
        int d = dstA[e];
        int pos = offs[d] + atomicAdd(&cnt[d], 1);
        srcs2[pos] = srcA[e];
        dsts2[pos] = d;
        perm[pos] = e;
    } else {
        int i = e - EE;
        if (i < NN){ srcs2[EE + i] = i; dsts2[EE + i] = i; }
    }
}

// loopf[n][c] = mean over incoming edges of ea[e][c], f32.
// Wave-per-node segmented gather: 64 lanes = 2 row-slots x 32 channels. Each
// 32-lane half reads one full 128B ea line per row (line-exact); perm indices
// for 4 row-pairs are fetched up front per iteration -> 4 independent load
// chains in flight (vs the old 1-deep serial perm->ea chain that ran at 6% VALU).
// Final shfl_xor(32) reduce + coalesced 128B store per node. Pre-warms L3 with
// ea for k_score.
__global__ __launch_bounds__(256) void k_loopf(const float* __restrict__ ea, const int* __restrict__ perm,
                                               const int* __restrict__ offs, float* __restrict__ loopf){
    int n = blockIdx.x * 4 + (threadIdx.x >> 6);
    if (n >= NN) return;
    int lane = threadIdx.x & 63;
    int c = lane & 31;
    int half = lane >> 5;

    int b = offs[n], e = offs[n + 1];
    int deg = e - b;
    float s = 0.f;
    int i = b + half;
    for (; i + 6 < e; i += 8){
        int e0 = perm[i], e1 = perm[i + 2], e2 = perm[i + 4], e3 = perm[i + 6];
        float v0 = ea[(size_t)e0 * 32 + c];
        float v1 = ea[(size_t)e1 * 32 + c];
        float v2 = ea[(size_t)e2 * 32 + c];
        float v3 = ea[(size_t)e3 * 32 + c];
        s += v0 + v1 + v2 + v3;
    }
    for (; i < e; i += 2) s += ea[(size_t)perm[i] * 32 + c];
    s += __shfl_xor(s, 32);
    if (half == 0) loopf[(size_t)n * 32 + c] = s / fmaxf((float)deg, 1.0f);
}

// ---------------- merged weight/input prep ----------------
// region 1: wt[c][k] = bf16(W[k][c]) for 8 DxD matrices (Wl0,Wl1,Wr0,Wr1,w10,w11,w20,w21)
// region 2: weA k_score A-fragments: weA[((l*8+t)*64+lane)*8+j] = bf16(We[l][q*8+j][t*16+m])
// region 3: nodes fp32 -> bf16
#define PREPW_T (8 * 16384)
#define PREPWE_T (LL * 4096)
#define PREPX_T (NN * DD / 4)

__global__ __launch_bounds__(256) void k_prep(const float* __restrict__ Wl, const float* __restrict__ Wr,
                                              const float* __restrict__ w1, const float* __restrict__ w2,
                                              short* __restrict__ wt,
                                              const float* __restrict__ We, short* __restrict__ weA,
                                              const float* __restrict__ x, short* __restrict__ xb){
    int gid = blockIdx.x * 256 + threadIdx.x;
    if (gid < PREPW_T){
        int mi = gid >> 14;
        int flat = gid & 16383;
        const float* base = (mi < 2) ? Wl : (mi < 4) ? Wr : (mi < 6) ? w1 : w2;
        const float* src = base + (size_t)(mi & 1) * 16384;
        int k = flat >> 7, c = flat & 127;
        wt[(size_t)mi * 16384 + c * 128 + k] = bf16c(src[flat]);
    } else if (gid < PREPW_T + PREPWE_T){
        int g2 = gid - PREPW_T;
        int j = g2 & 7;
        int lane = (g2 >> 3) & 63;
        int t = (g2 >> 9) & 7;
        int l = g2 >> 12;
        int q = lane >> 4, m = lane & 15;
        weA[g2] = bf16c(We[(size_t)l * 4096 + (q * 8 + j) * 128 + t * 16 + m]);
    } else {
        int i = gid - PREPW_T - PREPWE_T;
        if (i < PREPX_T){
            f32x4 v = *(const f32x4*)(x + (size_t)i * 4);
            short4v h = {bf16c(v[0]), bf16c(v[1]), bf16c(v[2]), bf16c(v[3])};
            *(short4v*)(xb + (size_t)i * 4) = h;
        }
    }
}

// ---------------- MFMA GEMM: C[r][c] = act( sum_k X[r][k] W[k][c] + bias[c] ) ----------------
// mode bit 1: write f32 natural; bit 2: write bf16; bit 4: bf16 write uses the
// permuted "score gather" row layout: channel c -> ushort offset
//   (c>>5)*32 + ((c>>2)&3)*8 + ((c>>4)&1)*4 + (c&3)
// so that k_score lanes read 16B contiguous chunks and 4 q-lanes cover one 64B segment.

__global__ __launch_bounds__(256) void k_mg(const short* __restrict__ Xb, const short* __restrict__ Wt,
                                            const float* __restrict__ bv, float* __restrict__ Yf,
                                            unsigned short* __restrict__ Yb, int act, int mode){
    int lane = threadIdx.x & 63;
    int wave = threadIdx.x >> 6;
    int q = lane >> 4;
    int m = lane & 15;
    int cw0 = wave * 32;
    int r0 = blockIdx.x * 64;

    short8 af[2][4];
    #pragma unroll
    for (int ct = 0; ct < 2; ct++)
        #pragma unroll
        for (int ks = 0; ks < 4; ks++)
            af[ct][ks] = *(const short8*)(Wt + (size_t)(cw0 + ct * 16 + m) * 128 + ks * 32 + q * 8);

    f32x4 bq[2];
    #pragma unroll
    for (int ct = 0; ct < 2; ct++)
        bq[ct] = *(const f32x4*)(bv + cw0 + ct * 16 + q * 4);

    #pragma unroll
    for (int rt = 0; rt < 4; rt++){
        int r = r0 + rt * 16 + m;
        int rc = (r < NN) ? r : NN - 1;
        short8 bf[4];
        #pragma unroll
        for (int ks = 0; ks < 4; ks++)
            bf[ks] = *(const short8*)(Xb + (size_t)rc * 128 + ks * 32 + q * 8);

        f32x4 ac0 = {0.f, 0.f, 0.f, 0.f};
        f32x4 ac1 = {0.f, 0.f, 0.f, 0.f};
        #pragma unroll
        for (int ks = 0; ks < 4; ks++){
            ac0 = __builtin_amdgcn_mfma_f32_16x16x32_bf16(af[0][ks], bf[ks], ac0, 0, 0, 0);
            ac1 = __builtin_amdgcn_mfma_f32_16x16x32_bf16(af[1][ks], bf[ks], ac1, 0, 0, 0);
        }
        int rr = r0 + rt * 16 + m;
        if (rr < NN){
            #pragma unroll
            for (int ct = 0; ct < 2; ct++){
                f32x4 a = ct ? ac1 : ac0;
                f32x4 v;
                #pragma unroll
                for (int j = 0; j < 4; j++){
                    float x = a[j] + bq[ct][j];
                    if (act) x = fmaxf(x, 0.f);
                    v[j] = x;
                }
                int c0 = cw0 + ct * 16 + q * 4;
                if (mode & 1)
                    *(f32x4*)(Yf + (size_t)rr * 128 + c0) = v;
                if (mode & 2){
                    short4v h = {bf16c(v[0]), bf16c(v[1]), bf16c(v[2]), bf16c(v[3])};
                    int oo = (mode & 4) ? (((c0 >> 5) << 5) + (q << 3) + (((c0 >> 4) & 1) << 2))
                                        : c0;
                    *(short4v*)(Yb + (size_t)rr * 128 + oo) = h;
                }
            }
        }
    }
}

// ---------------- fused edge-score kernel: 2 MFMA tiles per wave, one-shot ----------------
// alpha[pos][h] = sum_c att[h,c] * leaky(xl[src][c] + xr[dst][c] + (ea[perm[pos]]@We)[c])
// B-operand rows come straight from ea (f32, perm-gathered: 4 q-lanes x 32B = one full
// 128B line per row) or from loopf for self-loop tiles; converted bf16 in-register.
// xlb/xrb in the permuted layout (see k_mg). NON-persistent launch: the HW dispatcher
// provides a moving window over the dst-sorted tiles (L2 locality for xrb/alpha).

__global__ __launch_bounds__(256) void k_score(const float* __restrict__ ea, const float* __restrict__ loopf,
                                               const int* __restrict__ perm,
                                               const int* __restrict__ srcs2, const int* __restrict__ dsts2,
                                               const unsigned short* __restrict__ xlb,
                                               const unsigned short* __restrict__ xrb,
                                               const short* __restrict__ weA, const float* __restrict__ att,
                                               float* __restrict__ alpha){
    int lane = threadIdx.x & 63;
    int q = lane >> 4;
    int m = lane & 15;

    short8 af[8];
    #pragma unroll
    for (int t = 0; t < 8; t++)
        af[t] = *(const short8*)(weA + ((size_t)t * 64 + lane) * 8);

    int wid = (blockIdx.x * 256 + threadIdx.x) >> 6;
    int g = wid * 2;
    if (g >= NG) return;

    bool hB = (g + 1) < NG;
    int posA = g * 16 + m;
    int posB = hB ? posA + 16 : posA;

    int sA = srcs2[posA], dA = dsts2[posA];
    int sB = srcs2[posB], dB = dsts2[posB];
    int eA = perm[posA < EE ? posA : 0];
    int eB = perm[posB < EE ? posB : 0];

    // gathers: 16B/lane, 4 q-lanes contiguous per row (permuted layout)
    const unsigned short* pxA = xlb + (size_t)sA * 128 + q * 8;
    const unsigned short* prA = xrb + (size_t)dA * 128 + q * 8;
    const unsigned short* pxB = xlb + (size_t)sB * 128 + q * 8;
    const unsigned short* prB = xrb + (size_t)dB * 128 + q * 8;
    short8 gxA[4], grA[4], gxB[4], grB[4];
    #pragma unroll
    for (int u = 0; u < 4; u++){
        gxA[u] = *(const short8*)(pxA + u * 32);
        grA[u] = *(const short8*)(prA + u * 32);
        gxB[u] = *(const short8*)(pxB + u * 32);
        grB[u] = *(const short8*)(prB + u * 32);
    }

    // B-operand rows from ea / loopf, f32 -> bf16 in-register
    const float* rpA = (posA < EE) ? (ea + (size_t)eA * 32) : (loopf + (size_t)(posA - EE) * 32);
    const float* rpB = (posB < EE) ? (ea + (size_t)eB * 32) : (loopf + (size_t)(posB - EE) * 32);
    f32x4 va0 = *(const f32x4*)(rpA + q * 8);
    f32x4 va1 = *(const f32x4*)(rpA + q * 8 + 4);
    f32x4 vb0 = *(const f32x4*)(rpB + q * 8);
    f32x4 vb1 = *(const f32x4*)(rpB + q * 8 + 4);
    short8 bfA = {bf16c(va0[0]), bf16c(va0[1]), bf16c(va0[2]), bf16c(va0[3]),
                  bf16c(va1[0]), bf16c(va1[1]), bf16c(va1[2]), bf16c(va1[3])};
    short8 bfB = {bf16c(vb0[0]), bf16c(vb0[1]), bf16c(vb0[2]), bf16c(vb0[3]),
                  bf16c(vb1[0]), bf16c(vb1[1]), bf16c(vb1[2]), bf16c(vb1[3])};

    float psA[4] = {0.f,0.f,0.f,0.f}, psB[4] = {0.f,0.f,0.f,0.f};
    #pragma unroll
    for (int t = 0; t < 8; t++){
        f32x4 z = {0.f,0.f,0.f,0.f};
        f32x4 cA = __builtin_amdgcn_mfma_f32_16x16x32_bf16(af[t], bfA, z, 0, 0, 0);
        f32x4 cB = __builtin_amdgcn_mfma_f32_16x16x32_bf16(af[t], bfB, z, 0, 0, 0);
        f32x4 av = *(const f32x4*)(att + t * 16 + q * 4);
        int u = t >> 1, lo = (t & 1) * 4;
        #pragma unroll
        for (int r = 0; r < 4; r++){
            float ma = cA[r] + bf2f((unsigned short)gxA[u][lo + r]) + bf2f((unsigned short)grA[u][lo + r]);
            float mb = cB[r] + bf2f((unsigned short)gxB[u][lo + r]) + bf2f((unsigned short)grB[u][lo + r]);
            ma = (ma > 0.f) ? ma : 0.2f * ma;
            mb = (mb > 0.f) ? mb : 0.2f * mb;
            psA[t >> 1] = fmaf(av[r], ma, psA[t >> 1]);
            psB[t >> 1] = fmaf(av[r], mb, psB[t >> 1]);
        }
    }
    #pragma unroll
    for (int h = 0; h < 4; h++){
        psA[h] += __shfl_xor(psA[h], 16);
        psA[h] += __shfl_xor(psA[h], 32);
        psB[h] += __shfl_xor(psB[h], 16);
        psB[h] += __shfl_xor(psB[h], 32);
    }
    if (lane < 16){
        f32x4 oA = {psA[0], psA[1], psA[2], psA[3]};
        *(f32x4*)(alpha + (size_t)posA * 4) = oA;
        if (hB){
            f32x4 oB = {psB[0], psB[1], psB[2], psB[3]};
            *(f32x4*)(alpha + (size_t)posB * 4) = oB;
        }
    }
}

// ---------------- GATv2 softmax + aggregation (bf16 gathers, 2 adjacent ch/lane) ----------------
// lane owns channels {2*lane, 2*lane+1}; both in head h = lane>>4 -> single softmax state.
// xlb is in the permuted layout; per-lane ushort offset computed from channel.

__global__ __launch_bounds__(256) void k_gat2(const unsigned short* __restrict__ xlb,
                                              const int* __restrict__ srcs2, const int* __restrict__ offs,
                                              const float* __restrict__ alpha, const float* __restrict__ bias,
                                              unsigned short* __restrict__ out){
    int n = blockIdx.x * 4 + (threadIdx.x >> 6);
    int lane = threadIdx.x & 63;
    int c0 = lane * 2;
    int h = lane >> 4;
    // permuted ushort offset of channels {c0, c0+1} (adjacent in permuted layout since c0 even)
    int po = ((c0 >> 5) << 5) + (((c0 >> 2) & 3) << 3) + (((c0 >> 4) & 1) << 2) + (c0 & 3);

    int beg = offs[n];
    int deg = offs[n + 1] - beg;
    int cnt = deg + 1;   // + self-loop (position EE+n)

    float M = -INFINITY, S = 0.f, A0 = 0.f, A1 = 0.f;

    for (int i = 0; i < cnt; i += 4){
        float a[4]; unsigned x[4];
        #pragma unroll
        for (int u = 0; u < 4; u++){
            int iu = i + u;
            int p = (iu < deg) ? beg + iu : EE + n;
            int s = srcs2[p];
            a[u] = alpha[(size_t)p * 4 + h];
            x[u] = *(const unsigned*)(xlb + (size_t)s * 128 + po);
            if (iu >= cnt) a[u] = -INFINITY;
        }
        float nM = fmaxf(fmaxf(fmaxf(a[0], a[1]), fmaxf(a[2], a[3])), M);
        float rs = __expf(M - nM);
        float w0 = __expf(a[0] - nM);
        float w1 = __expf(a[1] - nM);
        float w2 = __expf(a[2] - nM);
        float w3 = __expf(a[3] - nM);
        S = S * rs + w0 + w1 + w2 + w3;
        A0 = A0 * rs + w0 * bf2f((unsigned short)(x[0] & 0xffffu))
                     + w1 * bf2f((unsigned short)(x[1] & 0xffffu))
                     + w2 * bf2f((unsigned short)(x[2] & 0xffffu))
                     + w3 * bf2f((unsigned short)(x[3] & 0xffffu));
        A1 = A1 * rs + w0 * bf2f((unsigned short)(x[0] >> 16))
                     + w1 * bf2f((unsigned short)(x[1] >> 16))
                     + w2 * bf2f((unsigned short)(x[2] >> 16))
                     + w3 * bf2f((unsigned short)(x[3] >> 16));
        M = nM;
    }
    float inv = 1.f / (S + 1e-16f);
    float v0 = A0 * inv + bias[c0];
    float v1 = A1 * inv + bias[c0 + 1];
    unsigned o = ((unsigned)(unsigned short)bf16c(v0)) | (((unsigned)(unsigned short)bf16c(v1)) << 16);
    *(unsigned*)(out + (size_t)n * 128 + c0) = o;
}

// ---------------- driver ----------------

extern "C" void kernel_launch(void* const* d_in, const int* in_sizes, int n_in,
                              void* d_out, int out_size, void* d_ws, size_t ws_size,
                              hipStream_t stream){
    const float* nodes = (const float*)d_in[0];
    const int*   ei    = (const int*)d_in[1];
    const float* ea    = (const float*)d_in[2];
    const float* Wl    = (const float*)d_in[3];
    const float* bl    = (const float*)d_in[4];
    const float* Wr    = (const float*)d_in[5];
    const float* br    = (const float*)d_in[6];
    const float* We    = (const float*)d_in[7];
    const float* att   = (const float*)d_in[8];
    const float* bias  = (const float*)d_in[9];
    const float* w1    = (const float*)d_in[10];
    const float* b1    = (const float*)d_in[11];
    const float* w2    = (const float*)d_in[12];
    const float* b2    = (const float*)d_in[13];
    const int* srcA = ei;
    const int* dstA = ei + EE;

    char* ws = (char*)d_ws;
    size_t off = 0;
    auto alloc = [&](size_t bytes) -> char* {
        off = (off + 255) & ~(size_t)255;
        char* p = ws + off;
        off += bytes;
        return p;
    };
    int*   deg   = (int*)alloc(NN * 4);
    int*   cnt   = (int*)alloc(NN * 4);
    int*   offs  = (int*)alloc((NN + 1) * 4);
    int*   bsum  = (int*)alloc(64 * 4);
    int*   srcs2 = (int*)alloc((size_t)TOT * 4);
    int*   dsts2 = (int*)alloc((size_t)TOT * 4);
    int*   perm  = (int*)alloc((size_t)EE * 4);
    float* loopf = (float*)alloc((size_t)NN * CC * 4);            // self-loop attr means, f32
    float* alpha = (float*)alloc((size_t)TOT * 4 * 4);
    short* wt    = (short*)alloc((size_t)8 * 16384 * 2);          // 8 transposed bf16 weights
    short* weA   = (short*)alloc((size_t)LL * 4096 * 2);          // k_score A-frag table
    short* xb    = (short*)alloc((size_t)NN * DD * 2);            // current x, bf16
    unsigned short* xlb = (unsigned short*)alloc((size_t)NN * DD * 2);
    unsigned short* xrb = (unsigned short*)alloc((size_t)NN * DD * 2);
    unsigned short* bgb = (unsigned short*)alloc((size_t)NN * DD * 2);  // gat2 out, bf16
    unsigned short* bhb = (unsigned short*)alloc((size_t)NN * DD * 2);  // MLP hidden, bf16
    unsigned short* bxb = (unsigned short*)alloc((size_t)NN * DD * 2);  // inter-layer x, bf16

    hipMemsetAsync(deg, 0, NN * 4, stream);
    hipMemsetAsync(cnt, 0, NN * 4, stream);
    k_hist<<<(EE + 255) / 256, 256, 0, stream>>>(dstA, deg);
    int nb = (NN + 1023) / 1024;
    k_scan1<<<nb, 1024, 0, stream>>>(deg, offs, bsum);
    k_scan2<<<1, 64, 0, stream>>>(bsum, nb);
    k_scan3<<<nb, 1024, 0, stream>>>(offs, bsum);
    k_scatter<<<(EE + NN + 255) / 256, 256, 0, stream>>>(srcA, dstA, offs, cnt, srcs2, dsts2, perm);
    k_loopf<<<(NN + 3) / 4, 256, 0, stream>>>(ea, perm, offs, loopf);
    k_prep<<<(PREPW_T + PREPWE_T + PREPX_T + 255) / 256, 256, 0, stream>>>(
        Wl, Wr, w1, w2, wt, We, weA, nodes, xb);

    const int GB = (NN + 63) / 64;   // 782
    const int SCORE_WAVES = (NG + 1) / 2;            // one wave per 2 adjacent tiles
    const int SCORE_BLOCKS = (SCORE_WAVES + 3) / 4;  // 4 waves per block
    short* wtWl = wt;
    short* wtWr = wt + 2 * 16384;
    short* wtw1 = wt + 4 * 16384;
    short* wtw2 = wt + 6 * 16384;

    const short* x = xb;
    for (int l = 0; l < LL; l++){
        // xl/xr projections written in the permuted score-gather layout (mode 2|4)
        k_mg<<<GB, 256, 0, stream>>>(x, wtWl + l * 16384, bl + l * DD, nullptr, xlb, 0, 6);
        k_mg<<<GB, 256, 0, stream>>>(x, wtWr + l * 16384, br + l * DD, nullptr, xrb, 0, 6);
        k_score<<<SCORE_BLOCKS, 256, 0, stream>>>(ea, loopf, perm, srcs2, dsts2, xlb, xrb,
                                                  weA + l * 4096, att + l * HH * CC, alpha);
        k_gat2<<<NN / 4, 256, 0, stream>>>(xlb, srcs2, offs, alpha, bias + l * DD, bgb);
        k_mg<<<GB, 256, 0, stream>>>((const short*)bgb, wtw1 + l * 16384, b1 + l * DD, nullptr, bhb, 1, 2);
        if (l == LL - 1)
            k_mg<<<GB, 256, 0, stream>>>((const short*)bhb, wtw2 + l * 16384, b2 + l * DD,
                                         (float*)d_out, nullptr, 0, 1);
        else
            k_mg<<<GB, 256, 0, stream>>>((const short*)bhb, wtw2 + l * 16384, b2 + l * DD,
                                         nullptr, bxb, 0, 2);
        x = (const short*)bxb;
    }
}

// Round 7
// 669.621 us; speedup vs baseline: 1.1072x; 1.0205x over previous
//
#include <hip/hip_runtime.h>
#include <math.h>

#define NN 50000
#define EE 800000
#define DD 128
#define HH 4
#define CC 32
#define LL 2
#define TOT (EE + NN)
#define NG (TOT / 16)

typedef __attribute__((ext_vector_type(8))) short short8;
typedef __attribute__((ext_vector_type(4))) short short4v;
typedef __attribute__((ext_vector_type(4))) float f32x4;
typedef __attribute__((ext_vector_type(4))) unsigned short ushort4v;

__device__ inline short bf16c(float f){
    unsigned u = __float_as_uint(f);
    u = (u + 0x7fffu + ((u >> 16) & 1u)) >> 16;
    return (short)u;
}
__device__ inline float bf2f(unsigned short h){
    return __uint_as_float(((unsigned)h) << 16);
}

// ---------------- edge sorting (by dst) ----------------

__global__ __launch_bounds__(256) void k_hist(const int* __restrict__ dstA, int* __restrict__ deg){
    int e = blockIdx.x * 256 + threadIdx.x;
    if (e < EE) atomicAdd(&deg[dstA[e]], 1);
}

__global__ __launch_bounds__(1024) void k_scan1(const int* __restrict__ deg, int* __restrict__ offs,
                                                int* __restrict__ bsum){
    __shared__ int buf[1024];
    int t = threadIdx.x;
    int i = blockIdx.x * 1024 + t;
    int v = (i < NN) ? deg[i] : 0;
    buf[t] = v;
    __syncthreads();
    for (int off = 1; off < 1024; off <<= 1){
        int x = (t >= off) ? buf[t - off] : 0;
        __syncthreads();
        buf[t] += x;
        __syncthreads();
    }
    if (i < NN) offs[i + 1] = buf[t];
    if (t == 1023) bsum[blockIdx.x] = buf[1023];
    if (i == 0) offs[0] = 0;
}

__global__ void k_scan2(int* __restrict__ bsum, int nb){
    if (threadIdx.x == 0){
        int s = 0;
        for (int b = 0; b < nb; b++){ int v = bsum[b]; bsum[b] = s; s += v; }
    }
}

__global__ __launch_bounds__(1024) void k_scan3(int* __restrict__ offs, const int* __restrict__ bsum){
    int i = blockIdx.x * 1024 + threadIdx.x;
    if (i < NN) offs[i + 1] += bsum[i >> 10];
}

// scatter pass (+ merged self-loop index fill): only small scattered 4B writes
// (perm/srcs2/dsts2 — their line working sets fit in L2 and write-combine).
__global__ __launch_bounds__(256) void k_scatter(const int* __restrict__ srcA, const int* __restrict__ dstA,
                                                 const int* __restrict__ offs, int* __restrict__ cnt,
                                                 int* __restrict__ srcs2, int* __restrict__ dsts2,
                                                 int* __restrict__ perm){
    int e = blockIdx.x * 256 + threadIdx.x;
    if (e < EE){
        int d = dstA[e];
        int pos = offs[d] + atomicAdd(&cnt[d], 1);
        srcs2[pos] = srcA[e];
        dsts2[pos] = d;
        perm[pos] = e;
    } else {
        int i = e - EE;
        if (i < NN){ srcs2[EE + i] = i; dsts2[EE + i] = i; }
    }
}

// loopf[n][c] = mean over incoming edges of ea[e][c], f32.
// Wave-per-node segmented gather: 64 lanes = 2 row-slots x 32 channels; 4 independent
// perm->ea chains in flight; line-exact 128B reads; shfl reduce; coalesced store.
__global__ __launch_bounds__(256) void k_loopf(const float* __restrict__ ea, const int* __restrict__ perm,
                                               const int* __restrict__ offs, float* __restrict__ loopf){
    int n = blockIdx.x * 4 + (threadIdx.x >> 6);
    if (n >= NN) return;
    int lane = threadIdx.x & 63;
    int c = lane & 31;
    int half = lane >> 5;

    int b = offs[n], e = offs[n + 1];
    int deg = e - b;
    float s = 0.f;
    int i = b + half;
    for (; i + 6 < e; i += 8){
        int e0 = perm[i], e1 = perm[i + 2], e2 = perm[i + 4], e3 = perm[i + 6];
        float v0 = ea[(size_t)e0 * 32 + c];
        float v1 = ea[(size_t)e1 * 32 + c];
        float v2 = ea[(size_t)e2 * 32 + c];
        float v3 = ea[(size_t)e3 * 32 + c];
        s += v0 + v1 + v2 + v3;
    }
    for (; i < e; i += 2) s += ea[(size_t)perm[i] * 32 + c];
    s += __shfl_xor(s, 32);
    if (half == 0) loopf[(size_t)n * 32 + c] = s / fmaxf((float)deg, 1.0f);
}

// ---------------- merged weight/input prep ----------------
#define PREPW_T (8 * 16384)
#define PREPWE_T (LL * 4096)
#define PREPX_T (NN * DD / 4)

__global__ __launch_bounds__(256) void k_prep(const float* __restrict__ Wl, const float* __restrict__ Wr,
                                              const float* __restrict__ w1, const float* __restrict__ w2,
                                              short* __restrict__ wt,
                                              const float* __restrict__ We, short* __restrict__ weA,
                                              const float* __restrict__ x, short* __restrict__ xb){
    int gid = blockIdx.x * 256 + threadIdx.x;
    if (gid < PREPW_T){
        int mi = gid >> 14;
        int flat = gid & 16383;
        const float* base = (mi < 2) ? Wl : (mi < 4) ? Wr : (mi < 6) ? w1 : w2;
        const float* src = base + (size_t)(mi & 1) * 16384;
        int k = flat >> 7, c = flat & 127;
        wt[(size_t)mi * 16384 + c * 128 + k] = bf16c(src[flat]);
    } else if (gid < PREPW_T + PREPWE_T){
        int g2 = gid - PREPW_T;
        int j = g2 & 7;
        int lane = (g2 >> 3) & 63;
        int t = (g2 >> 9) & 7;
        int l = g2 >> 12;
        int q = lane >> 4, m = lane & 15;
        weA[g2] = bf16c(We[(size_t)l * 4096 + (q * 8 + j) * 128 + t * 16 + m]);
    } else {
        int i = gid - PREPW_T - PREPWE_T;
        if (i < PREPX_T){
            f32x4 v = *(const f32x4*)(x + (size_t)i * 4);
            short4v h = {bf16c(v[0]), bf16c(v[1]), bf16c(v[2]), bf16c(v[3])};
            *(short4v*)(xb + (size_t)i * 4) = h;
        }
    }
}

// ---------------- MFMA GEMM: C[r][c] = act( sum_k X[r][k] W[k][c] + bias[c] ) ----------------
// mode bit 1: write f32 natural; bit 2: write bf16; bit 4: permuted score-gather layout.

__global__ __launch_bounds__(256) void k_mg(const short* __restrict__ Xb, const short* __restrict__ Wt,
                                            const float* __restrict__ bv, float* __restrict__ Yf,
                                            unsigned short* __restrict__ Yb, int act, int mode){
    int lane = threadIdx.x & 63;
    int wave = threadIdx.x >> 6;
    int q = lane >> 4;
    int m = lane & 15;
    int cw0 = wave * 32;
    int r0 = blockIdx.x * 64;

    short8 af[2][4];
    #pragma unroll
    for (int ct = 0; ct < 2; ct++)
        #pragma unroll
        for (int ks = 0; ks < 4; ks++)
            af[ct][ks] = *(const short8*)(Wt + (size_t)(cw0 + ct * 16 + m) * 128 + ks * 32 + q * 8);

    f32x4 bq[2];
    #pragma unroll
    for (int ct = 0; ct < 2; ct++)
        bq[ct] = *(const f32x4*)(bv + cw0 + ct * 16 + q * 4);

    #pragma unroll
    for (int rt = 0; rt < 4; rt++){
        int r = r0 + rt * 16 + m;
        int rc = (r < NN) ? r : NN - 1;
        short8 bf[4];
        #pragma unroll
        for (int ks = 0; ks < 4; ks++)
            bf[ks] = *(const short8*)(Xb + (size_t)rc * 128 + ks * 32 + q * 8);

        f32x4 ac0 = {0.f, 0.f, 0.f, 0.f};
        f32x4 ac1 = {0.f, 0.f, 0.f, 0.f};
        #pragma unroll
        for (int ks = 0; ks < 4; ks++){
            ac0 = __builtin_amdgcn_mfma_f32_16x16x32_bf16(af[0][ks], bf[ks], ac0, 0, 0, 0);
            ac1 = __builtin_amdgcn_mfma_f32_16x16x32_bf16(af[1][ks], bf[ks], ac1, 0, 0, 0);
        }
        int rr = r0 + rt * 16 + m;
        if (rr < NN){
            #pragma unroll
            for (int ct = 0; ct < 2; ct++){
                f32x4 a = ct ? ac1 : ac0;
                f32x4 v;
                #pragma unroll
                for (int j = 0; j < 4; j++){
                    float x = a[j] + bq[ct][j];
                    if (act) x = fmaxf(x, 0.f);
                    v[j] = x;
                }
                int c0 = cw0 + ct * 16 + q * 4;
                if (mode & 1)
                    *(f32x4*)(Yf + (size_t)rr * 128 + c0) = v;
                if (mode & 2){
                    short4v h = {bf16c(v[0]), bf16c(v[1]), bf16c(v[2]), bf16c(v[3])};
                    int oo = (mode & 4) ? (((c0 >> 5) << 5) + (q << 3) + (((c0 >> 4) & 1) << 2))
                                        : c0;
                    *(short4v*)(Yb + (size_t)rr * 128 + oo) = h;
                }
            }
        }
    }
}

// ---------------- fused xl/xr projection: reads X once, writes both permuted outputs ----

__global__ __launch_bounds__(256) void k_mg2(const short* __restrict__ Xb,
                                             const short* __restrict__ WtL, const short* __restrict__ WtR,
                                             const float* __restrict__ bvL, const float* __restrict__ bvR,
                                             unsigned short* __restrict__ YL, unsigned short* __restrict__ YR){
    int lane = threadIdx.x & 63;
    int wave = threadIdx.x >> 6;
    int q = lane >> 4;
    int m = lane & 15;
    int cw0 = wave * 32;
    int r0 = blockIdx.x * 64;

    short8 afL[2][4], afR[2][4];
    #pragma unroll
    for (int ct = 0; ct < 2; ct++)
        #pragma unroll
        for (int ks = 0; ks < 4; ks++){
            afL[ct][ks] = *(const short8*)(WtL + (size_t)(cw0 + ct * 16 + m) * 128 + ks * 32 + q * 8);
            afR[ct][ks] = *(const short8*)(WtR + (size_t)(cw0 + ct * 16 + m) * 128 + ks * 32 + q * 8);
        }

    f32x4 bqL[2], bqR[2];
    #pragma unroll
    for (int ct = 0; ct < 2; ct++){
        bqL[ct] = *(const f32x4*)(bvL + cw0 + ct * 16 + q * 4);
        bqR[ct] = *(const f32x4*)(bvR + cw0 + ct * 16 + q * 4);
    }

    #pragma unroll
    for (int rt = 0; rt < 4; rt++){
        int r = r0 + rt * 16 + m;
        int rc = (r < NN) ? r : NN - 1;
        short8 bf[4];
        #pragma unroll
        for (int ks = 0; ks < 4; ks++)
            bf[ks] = *(const short8*)(Xb + (size_t)rc * 128 + ks * 32 + q * 8);

        f32x4 aL0 = {0.f,0.f,0.f,0.f}, aL1 = {0.f,0.f,0.f,0.f};
        f32x4 aR0 = {0.f,0.f,0.f,0.f}, aR1 = {0.f,0.f,0.f,0.f};
        #pragma unroll
        for (int ks = 0; ks < 4; ks++){
            aL0 = __builtin_amdgcn_mfma_f32_16x16x32_bf16(afL[0][ks], bf[ks], aL0, 0, 0, 0);
            aL1 = __builtin_amdgcn_mfma_f32_16x16x32_bf16(afL[1][ks], bf[ks], aL1, 0, 0, 0);
            aR0 = __builtin_amdgcn_mfma_f32_16x16x32_bf16(afR[0][ks], bf[ks], aR0, 0, 0, 0);
            aR1 = __builtin_amdgcn_mfma_f32_16x16x32_bf16(afR[1][ks], bf[ks], aR1, 0, 0, 0);
        }
        if (r < NN){
            #pragma unroll
            for (int ct = 0; ct < 2; ct++){
                f32x4 aL = ct ? aL1 : aL0;
                f32x4 aR = ct ? aR1 : aR0;
                int c0 = cw0 + ct * 16 + q * 4;
                int oo = ((c0 >> 5) << 5) + (q << 3) + (((c0 >> 4) & 1) << 2);
                short4v hL = {bf16c(aL[0] + bqL[ct][0]), bf16c(aL[1] + bqL[ct][1]),
                              bf16c(aL[2] + bqL[ct][2]), bf16c(aL[3] + bqL[ct][3])};
                short4v hR = {bf16c(aR[0] + bqR[ct][0]), bf16c(aR[1] + bqR[ct][1]),
                              bf16c(aR[2] + bqR[ct][2]), bf16c(aR[3] + bqR[ct][3])};
                *(short4v*)(YL + (size_t)r * 128 + oo) = hL;
                *(short4v*)(YR + (size_t)r * 128 + oo) = hR;
            }
        }
    }
}

// ---------------- fused edge-score kernel: 2 MFMA tiles per wave, one-shot --------------
// 512-thread blocks (8 one-shot waves): halves block-dispatch count to raise wave
// residency (R6 measured occupancy 19% with 4-wave blocks -> BW concurrency-capped at
// 2.25 TB/s). Per-wave code identical; contiguous tile pairs per wave (locality rule).

__global__ __launch_bounds__(512) void k_score(const float* __restrict__ ea, const float* __restrict__ loopf,
                                               const int* __restrict__ perm,
                                               const int* __restrict__ srcs2, const int* __restrict__ dsts2,
                                               const unsigned short* __restrict__ xlb,
                                               const unsigned short* __restrict__ xrb,
                                               const short* __restrict__ weA, const float* __restrict__ att,
                                               float* __restrict__ alpha){
    int lane = threadIdx.x & 63;
    int q = lane >> 4;
    int m = lane & 15;

    short8 af[8];
    #pragma unroll
    for (int t = 0; t < 8; t++)
        af[t] = *(const short8*)(weA + ((size_t)t * 64 + lane) * 8);

    int wid = (blockIdx.x * 512 + threadIdx.x) >> 6;
    int g = wid * 2;
    if (g >= NG) return;

    bool hB = (g + 1) < NG;
    int posA = g * 16 + m;
    int posB = hB ? posA + 16 : posA;

    int sA = srcs2[posA], dA = dsts2[posA];
    int sB = srcs2[posB], dB = dsts2[posB];
    int eA = perm[posA < EE ? posA : 0];
    int eB = perm[posB < EE ? posB : 0];

    // gathers: 16B/lane, 4 q-lanes contiguous per row (permuted layout)
    const unsigned short* pxA = xlb + (size_t)sA * 128 + q * 8;
    const unsigned short* prA = xrb + (size_t)dA * 128 + q * 8;
    const unsigned short* pxB = xlb + (size_t)sB * 128 + q * 8;
    const unsigned short* prB = xrb + (size_t)dB * 128 + q * 8;
    short8 gxA[4], grA[4], gxB[4], grB[4];
    #pragma unroll
    for (int u = 0; u < 4; u++){
        gxA[u] = *(const short8*)(pxA + u * 32);
        grA[u] = *(const short8*)(prA + u * 32);
        gxB[u] = *(const short8*)(pxB + u * 32);
        grB[u] = *(const short8*)(prB + u * 32);
    }

    // B-operand rows from ea / loopf, f32 -> bf16 in-register
    const float* rpA = (posA < EE) ? (ea + (size_t)eA * 32) : (loopf + (size_t)(posA - EE) * 32);
    const float* rpB = (posB < EE) ? (ea + (size_t)eB * 32) : (loopf + (size_t)(posB - EE) * 32);
    f32x4 va0 = *(const f32x4*)(rpA + q * 8);
    f32x4 va1 = *(const f32x4*)(rpA + q * 8 + 4);
    f32x4 vb0 = *(const f32x4*)(rpB + q * 8);
    f32x4 vb1 = *(const f32x4*)(rpB + q * 8 + 4);
    short8 bfA = {bf16c(va0[0]), bf16c(va0[1]), bf16c(va0[2]), bf16c(va0[3]),
                  bf16c(va1[0]), bf16c(va1[1]), bf16c(va1[2]), bf16c(va1[3])};
    short8 bfB = {bf16c(vb0[0]), bf16c(vb0[1]), bf16c(vb0[2]), bf16c(vb0[3]),
                  bf16c(vb1[0]), bf16c(vb1[1]), bf16c(vb1[2]), bf16c(vb1[3])};

    float psA[4] = {0.f,0.f,0.f,0.f}, psB[4] = {0.f,0.f,0.f,0.f};
    #pragma unroll
    for (int t = 0; t < 8; t++){
        f32x4 z = {0.f,0.f,0.f,0.f};
        f32x4 cA = __builtin_amdgcn_mfma_f32_16x16x32_bf16(af[t], bfA, z, 0, 0, 0);
        f32x4 cB = __builtin_amdgcn_mfma_f32_16x16x32_bf16(af[t], bfB, z, 0, 0, 0);
        f32x4 av = *(const f32x4*)(att + t * 16 + q * 4);
        int u = t >> 1, lo = (t & 1) * 4;
        #pragma unroll
        for (int r = 0; r < 4; r++){
            float ma = cA[r] + bf2f((unsigned short)gxA[u][lo + r]) + bf2f((unsigned short)grA[u][lo + r]);
            float mb = cB[r] + bf2f((unsigned short)gxB[u][lo + r]) + bf2f((unsigned short)grB[u][lo + r]);
            ma = (ma > 0.f) ? ma : 0.2f * ma;
            mb = (mb > 0.f) ? mb : 0.2f * mb;
            psA[t >> 1] = fmaf(av[r], ma, psA[t >> 1]);
            psB[t >> 1] = fmaf(av[r], mb, psB[t >> 1]);
        }
    }
    #pragma unroll
    for (int h = 0; h < 4; h++){
        psA[h] += __shfl_xor(psA[h], 16);
        psA[h] += __shfl_xor(psA[h], 32);
        psB[h] += __shfl_xor(psB[h], 16);
        psB[h] += __shfl_xor(psB[h], 32);
    }
    if (lane < 16){
        f32x4 oA = {psA[0], psA[1], psA[2], psA[3]};
        *(f32x4*)(alpha + (size_t)posA * 4) = oA;
        if (hB){
            f32x4 oB = {psB[0], psB[1], psB[2], psB[3]};
            *(f32x4*)(alpha + (size_t)posB * 4) = oB;
        }
    }
}

// ---------------- GATv2 softmax + aggregation (bf16 gathers, 2 adjacent ch/lane) --------
// 512-thread blocks (8 node-waves) for the same residency reason as k_score.

__global__ __launch_bounds__(512) void k_gat2(const unsigned short* __restrict__ xlb,
                                              const int* __restrict__ srcs2, const int* __restrict__ offs,
                                              const float* __restrict__ alpha, const float* __restrict__ bias,
                                              unsigned short* __restrict__ out){
    int n = blockIdx.x * 8 + (threadIdx.x >> 6);
    if (n >= NN) return;
    int lane = threadIdx.x & 63;
    int c0 = lane * 2;
    int h = lane >> 4;
    // permuted ushort offset of channels {c0, c0+1} (adjacent in permuted layout since c0 even)
    int po = ((c0 >> 5) << 5) + (((c0 >> 2) & 3) << 3) + (((c0 >> 4) & 1) << 2) + (c0 & 3);

    int beg = offs[n];
    int deg = offs[n + 1] - beg;
    int cnt = deg + 1;   // + self-loop (position EE+n)

    float M = -INFINITY, S = 0.f, A0 = 0.f, A1 = 0.f;

    for (int i = 0; i < cnt; i += 4){
        float a[4]; unsigned x[4];
        #pragma unroll
        for (int u = 0; u < 4; u++){
            int iu = i + u;
            int p = (iu < deg) ? beg + iu : EE + n;
            int s = srcs2[p];
            a[u] = alpha[(size_t)p * 4 + h];
            x[u] = *(const unsigned*)(xlb + (size_t)s * 128 + po);
            if (iu >= cnt) a[u] = -INFINITY;
        }
        float nM = fmaxf(fmaxf(fmaxf(a[0], a[1]), fmaxf(a[2], a[3])), M);
        float rs = __expf(M - nM);
        float w0 = __expf(a[0] - nM);
        float w1 = __expf(a[1] - nM);
        float w2 = __expf(a[2] - nM);
        float w3 = __expf(a[3] - nM);
        S = S * rs + w0 + w1 + w2 + w3;
        A0 = A0 * rs + w0 * bf2f((unsigned short)(x[0] & 0xffffu))
                     + w1 * bf2f((unsigned short)(x[1] & 0xffffu))
                     + w2 * bf2f((unsigned short)(x[2] & 0xffffu))
                     + w3 * bf2f((unsigned short)(x[3] & 0xffffu));
        A1 = A1 * rs + w0 * bf2f((unsigned short)(x[0] >> 16))
                     + w1 * bf2f((unsigned short)(x[1] >> 16))
                     + w2 * bf2f((unsigned short)(x[2] >> 16))
                     + w3 * bf2f((unsigned short)(x[3] >> 16));
        M = nM;
    }
    float inv = 1.f / (S + 1e-16f);
    float v0 = A0 * inv + bias[c0];
    float v1 = A1 * inv + bias[c0 + 1];
    unsigned o = ((unsigned)(unsigned short)bf16c(v0)) | (((unsigned)(unsigned short)bf16c(v1)) << 16);
    *(unsigned*)(out + (size_t)n * 128 + c0) = o;
}

// ---------------- driver ----------------

extern "C" void kernel_launch(void* const* d_in, const int* in_sizes, int n_in,
                              void* d_out, int out_size, void* d_ws, size_t ws_size,
                              hipStream_t stream){
    const float* nodes = (const float*)d_in[0];
    const int*   ei    = (const int*)d_in[1];
    const float* ea    = (const float*)d_in[2];
    const float* Wl    = (const float*)d_in[3];
    const float* bl    = (const float*)d_in[4];
    const float* Wr    = (const float*)d_in[5];
    const float* br    = (const float*)d_in[6];
    const float* We    = (const float*)d_in[7];
    const float* att   = (const float*)d_in[8];
    const float* bias  = (const float*)d_in[9];
    const float* w1    = (const float*)d_in[10];
    const float* b1    = (const float*)d_in[11];
    const float* w2    = (const float*)d_in[12];
    const float* b2    = (const float*)d_in[13];
    const int* srcA = ei;
    const int* dstA = ei + EE;

    char* ws = (char*)d_ws;
    size_t off = 0;
    auto alloc = [&](size_t bytes) -> char* {
        off = (off + 255) & ~(size_t)255;
        char* p = ws + off;
        off += bytes;
        return p;
    };
    int*   deg   = (int*)alloc(NN * 4);
    int*   cnt   = (int*)alloc(NN * 4);
    int*   offs  = (int*)alloc((NN + 1) * 4);
    int*   bsum  = (int*)alloc(64 * 4);
    int*   srcs2 = (int*)alloc((size_t)TOT * 4);
    int*   dsts2 = (int*)alloc((size_t)TOT * 4);
    int*   perm  = (int*)alloc((size_t)EE * 4);
    float* loopf = (float*)alloc((size_t)NN * CC * 4);            // self-loop attr means, f32
    float* alpha = (float*)alloc((size_t)TOT * 4 * 4);
    short* wt    = (short*)alloc((size_t)8 * 16384 * 2);          // 8 transposed bf16 weights
    short* weA   = (short*)alloc((size_t)LL * 4096 * 2);          // k_score A-frag table
    short* xb    = (short*)alloc((size_t)NN * DD * 2);            // current x, bf16
    unsigned short* xlb = (unsigned short*)alloc((size_t)NN * DD * 2);
    unsigned short* xrb = (unsigned short*)alloc((size_t)NN * DD * 2);
    unsigned short* bgb = (unsigned short*)alloc((size_t)NN * DD * 2);  // gat2 out, bf16
    unsigned short* bhb = (unsigned short*)alloc((size_t)NN * DD * 2);  // MLP hidden, bf16
    unsigned short* bxb = (unsigned short*)alloc((size_t)NN * DD * 2);  // inter-layer x, bf16

    hipMemsetAsync(deg, 0, NN * 4, stream);
    hipMemsetAsync(cnt, 0, NN * 4, stream);
    k_hist<<<(EE + 255) / 256, 256, 0, stream>>>(dstA, deg);
    int nb = (NN + 1023) / 1024;
    k_scan1<<<nb, 1024, 0, stream>>>(deg, offs, bsum);
    k_scan2<<<1, 64, 0, stream>>>(bsum, nb);
    k_scan3<<<nb, 1024, 0, stream>>>(offs, bsum);
    k_scatter<<<(EE + NN + 255) / 256, 256, 0, stream>>>(srcA, dstA, offs, cnt, srcs2, dsts2, perm);
    k_loopf<<<(NN + 3) / 4, 256, 0, stream>>>(ea, perm, offs, loopf);
    k_prep<<<(PREPW_T + PREPWE_T + PREPX_T + 255) / 256, 256, 0, stream>>>(
        Wl, Wr, w1, w2, wt, We, weA, nodes, xb);

    const int GB = (NN + 63) / 64;   // 782
    const int SCORE_WAVES = (NG + 1) / 2;            // one wave per 2 adjacent tiles
    const int SCORE_BLOCKS = (SCORE_WAVES + 7) / 8;  // 8 waves per block (512 threads)
    short* wtWl = wt;
    short* wtWr = wt + 2 * 16384;
    short* wtw1 = wt + 4 * 16384;
    short* wtw2 = wt + 6 * 16384;

    const short* x = xb;
    for (int l = 0; l < LL; l++){
        // fused xl/xr projections (reads x once, permuted score-gather layout outputs)
        k_mg2<<<GB, 256, 0, stream>>>(x, wtWl + l * 16384, wtWr + l * 16384,
                                      bl + l * DD, br + l * DD, xlb, xrb);
        k_score<<<SCORE_BLOCKS, 512, 0, stream>>>(ea, loopf, perm, srcs2, dsts2, xlb, xrb,
                                                  weA + l * 4096, att + l * HH * CC, alpha);
        k_gat2<<<(NN + 7) / 8, 512, 0, stream>>>(xlb, srcs2, offs, alpha, bias + l * DD, bgb);
        k_mg<<<GB, 256, 0, stream>>>((const short*)bgb, wtw1 + l * 16384, b1 + l * DD, nullptr, bhb, 1, 2);
        if (l == LL - 1)
            k_mg<<<GB, 256, 0, stream>>>((const short*)bhb, wtw2 + l * 16384, b2 + l * DD,
                                         (float*)d_out, nullptr, 0, 1);
        else
            k_mg<<<GB, 256, 0, stream>>>((const short*)bhb, wtw2 + l * 16384, b2 + l * DD,
                                         nullptr, bxb, 0, 2);
        x = (const short*)bxb;
    }
}